// Round 1
// baseline (168.663 us; speedup 1.0000x reference)
//
#include <hip/hip_runtime.h>
#include <hip/hip_bf16.h>

// RoPE: out[b,s,2j]   = cos(a)*x[b,s,2j] - sin(a)*x[b,s,2j+1]
//       out[b,s,2j+1] = sin(a)*x[b,s,2j] + cos(a)*x[b,s,2j+1]
// a = pos * theta^(-j/32), pos = token_positions[b,s], j in [0,32)
// d_k = 64 -> 16 float4 per row; one thread handles one float4 (2 pairs).

#define DK4 16  // float4 chunks per d_k row

__global__ __launch_bounds__(256) void rope_kernel(
    const float* __restrict__ x,
    const int* __restrict__ tp,
    float* __restrict__ out,
    int n4)  // total float4 count
{
    int idx = blockIdx.x * blockDim.x + threadIdx.x;
    if (idx >= n4) return;

    int quad = idx & (DK4 - 1);   // which float4 within the 64-elem row
    int p    = idx >> 4;          // flat (b,s) index
    int pos  = tp[p];

    const float4* __restrict__ x4 = (const float4*)x;
    float4 v = x4[idx];

    // pair indices j0 = 2*quad, j1 = 2*quad+1
    // theta^(-j/32) = exp2(-j * log2(10000)/32)
    const double L = 0.4152410118609203;  // log2(10000)/32
    double j0 = (double)(quad << 1);
    double a0 = (double)pos * exp2(-j0 * L);
    double a1 = (double)pos * exp2(-(j0 + 1.0) * L);

    double s0, c0, s1, c1;
    sincos(a0, &s0, &c0);
    sincos(a1, &s1, &c1);

    float4 r;
    r.x = (float)(c0 * (double)v.x - s0 * (double)v.y);
    r.y = (float)(s0 * (double)v.x + c0 * (double)v.y);
    r.z = (float)(c1 * (double)v.z - s1 * (double)v.w);
    r.w = (float)(s1 * (double)v.z + c1 * (double)v.w);

    float4* __restrict__ o4 = (float4*)out;
    o4[idx] = r;
}

extern "C" void kernel_launch(void* const* d_in, const int* in_sizes, int n_in,
                              void* d_out, int out_size, void* d_ws, size_t ws_size,
                              hipStream_t stream) {
    const float* x  = (const float*)d_in[0];   // (4, 8192, 64) fp32
    const int*   tp = (const int*)d_in[1];     // (4, 8192) int32
    // d_in[2] = rope_buffer (8192,64,64) fp32 -- intentionally unused.
    float* out = (float*)d_out;

    int n  = in_sizes[0];      // 2097152
    int n4 = n / 4;            // 524288 float4s
    int block = 256;
    int grid = (n4 + block - 1) / block;
    rope_kernel<<<grid, block, 0, stream>>>(x, tp, out, n4);
}

// Round 2
// 168.430 us; speedup vs baseline: 1.0014x; 1.0014x over previous
//
#include <hip/hip_runtime.h>
#include <hip/hip_bf16.h>

// RoPE: out[b,s,2j]   = cos(a)*x[b,s,2j] - sin(a)*x[b,s,2j+1]
//       out[b,s,2j+1] = sin(a)*x[b,s,2j] + cos(a)*x[b,s,2j+1]
// a = pos * theta^(-j/32), pos = token_positions[b,s], j in [0,32)
// d_k = 64 -> 16 float4 per row; one thread handles one float4 (2 pairs).
//
// R1: fp64 sincos was ~160us of VALU latency (software fp64 transcendental).
// fp32 sinf/cosf: angle<=8191 rad, fp32 rounding error ~1e-3 rad -> out err
// ~5e-3 << 0.102 threshold. Kernel becomes memory-bound (~16.9 MB traffic).

#define DK4 16  // float4 chunks per d_k row

__global__ __launch_bounds__(256) void rope_kernel(
    const float* __restrict__ x,
    const int* __restrict__ tp,
    float* __restrict__ out,
    int n4)  // total float4 count
{
    int idx = blockIdx.x * blockDim.x + threadIdx.x;
    if (idx >= n4) return;

    int quad = idx & (DK4 - 1);   // which float4 within the 64-elem row
    int p    = idx >> 4;          // flat (b,s) index
    int pos  = tp[p];

    const float4* __restrict__ x4 = (const float4*)x;
    float4 v = x4[idx];

    // pair indices j0 = 2*quad, j1 = 2*quad+1
    // theta^(-j/32) = exp2(-j * log2(10000)/32)
    const float L = 0.41524101186092028f;  // log2(10000)/32
    float fpos = (float)pos;
    float j0 = (float)(quad << 1);
    float a0 = fpos * exp2f(-j0 * L);
    float a1 = fpos * exp2f(-(j0 + 1.0f) * L);

    float s0 = sinf(a0), c0 = cosf(a0);
    float s1 = sinf(a1), c1 = cosf(a1);

    float4 r;
    r.x = c0 * v.x - s0 * v.y;
    r.y = s0 * v.x + c0 * v.y;
    r.z = c1 * v.z - s1 * v.w;
    r.w = s1 * v.z + c1 * v.w;

    float4* __restrict__ o4 = (float4*)out;
    o4[idx] = r;
}

extern "C" void kernel_launch(void* const* d_in, const int* in_sizes, int n_in,
                              void* d_out, int out_size, void* d_ws, size_t ws_size,
                              hipStream_t stream) {
    const float* x  = (const float*)d_in[0];   // (4, 8192, 64) fp32
    const int*   tp = (const int*)d_in[1];     // (4, 8192) int32
    // d_in[2] = rope_buffer (8192,64,64) fp32 -- intentionally unused.
    float* out = (float*)d_out;

    int n  = in_sizes[0];      // 2097152
    int n4 = n / 4;            // 524288 float4s
    int block = 256;
    int grid = (n4 + block - 1) / block;
    rope_kernel<<<grid, block, 0, stream>>>(x, tp, out, n4);
}

// Round 3
// 167.939 us; speedup vs baseline: 1.0043x; 1.0029x over previous
//
#include <hip/hip_runtime.h>
#include <hip/hip_bf16.h>

// RoPE: out[b,s,2j]   = cos(a)*x[b,s,2j] - sin(a)*x[b,s,2j+1]
//       out[b,s,2j+1] = sin(a)*x[b,s,2j] + cos(a)*x[b,s,2j+1]
// a = pos * theta^(-j/32), pos = token_positions[b,s], j in [0,32)
//
// R3: hardware trig path. v_sin_f32/v_cos_f32 take input in REVOLUTIONS
// (sin(S0*2pi)), so compute rev = pos * theta^(-j/32) / (2pi) directly:
//   rev = pos * exp2(-(j*log2(theta)/32 + log2(2pi)))
// one v_exp_f32 + v_fract_f32 + v_sin/v_cos per pair (~6 VALU ops vs ~80
// for ocml sinf/cosf large-arg reduction). Reduction error: rev <= 1304,
// fract in fp32 -> ~1.6e-4 rev ~= 1e-3 rad -> out err ~5e-3 << 0.102 thr.
//
// NOTE: dur_us has a ~158us floor from the harness's two 536MB d_ws poison
// fills (seen as fillBufferAligned@79us in rocprof); our kernel is the
// remaining ~10us slice.

#define DK4 16  // float4 chunks per d_k row

__global__ __launch_bounds__(256) void rope_kernel(
    const float* __restrict__ x,
    const int* __restrict__ tp,
    float* __restrict__ out,
    int n4)  // total float4 count
{
    int idx = blockIdx.x * blockDim.x + threadIdx.x;
    if (idx >= n4) return;

    int quad = idx & (DK4 - 1);   // which float4 within the 64-elem row
    int p    = idx >> 4;          // flat (b,s) index

    int pos = tp[p];
    const float4* __restrict__ x4 = (const float4*)x;
    float4 v = x4[idx];

    const float L = 0.41524101186092028f;  // log2(10000)/32
    const float C = 2.6514961294723187f;   // log2(2*pi)
    float fpos = (float)pos;
    float j0 = (float)(quad << 1);

    // revolutions = pos * theta^(-j/32) / (2*pi)
    float rev0 = fpos * __builtin_amdgcn_exp2f(-(j0 * L) - C);
    float rev1 = fpos * __builtin_amdgcn_exp2f(-(j0 * L) - (L + C));
    rev0 -= floorf(rev0);   // v_fract_f32
    rev1 -= floorf(rev1);

    float s0 = __builtin_amdgcn_sinf(rev0);  // sin(2*pi*rev0)
    float c0 = __builtin_amdgcn_cosf(rev0);
    float s1 = __builtin_amdgcn_sinf(rev1);
    float c1 = __builtin_amdgcn_cosf(rev1);

    float4 r;
    r.x = c0 * v.x - s0 * v.y;
    r.y = s0 * v.x + c0 * v.y;
    r.z = c1 * v.z - s1 * v.w;
    r.w = s1 * v.z + c1 * v.w;

    float4* __restrict__ o4 = (float4*)out;
    o4[idx] = r;
}

extern "C" void kernel_launch(void* const* d_in, const int* in_sizes, int n_in,
                              void* d_out, int out_size, void* d_ws, size_t ws_size,
                              hipStream_t stream) {
    const float* x  = (const float*)d_in[0];   // (4, 8192, 64) fp32
    const int*   tp = (const int*)d_in[1];     // (4, 8192) int32
    // d_in[2] = rope_buffer (8192,64,64) fp32 -- intentionally unused.
    float* out = (float*)d_out;

    int n  = in_sizes[0];      // 2097152
    int n4 = n / 4;            // 524288 float4s
    int block = 256;
    int grid = (n4 + block - 1) / block;
    rope_kernel<<<grid, block, 0, stream>>>(x, tp, out, n4);
}